// Round 12
// baseline (1889.132 us; speedup 1.0000x reference)
//
#include <hip/hip_runtime.h>

// ---------------- problem constants ----------------
#define BB 16
#define SS 100
#define HH 400      // hidden per direction
#define H2 800
#define G4 1600     // 4*H gate rows
#define DIN0 150    // WE+PE
#define KP0 160     // padded layer-0 K (150 -> 160, K%32==0)
#define LWGS 25     // LSTM WGs per direction (16 hidden units each, 4 waves)

// ---------------- workspace layout (float offsets) ----------------
#define OFF_GF   240000ULL     // 2,560,000 (g0f / g1f / ua)
#define OFF_GB   2800000ULL    // 2,560,000 (g0b / g1b / wa)
#define OFF_H1   5360000ULL    // 1,280,000
#define OFF_OUT2 6640000ULL    // 1,280,000
#define OFF_NLL  8078400ULL    // 1,600
#define OFF_EXH  8081600ULL    // u16 exchange planes (exhi then exlo, contiguous)
#define EX_U16_PER_PLANE 1331200ULL   // 2 dir * 100 steps * 13 kt * 64 * 8

typedef _Float16 f16x8 __attribute__((ext_vector_type(8)));
typedef float    f32x4 __attribute__((ext_vector_type(4)));

// poison check: u32 half == 0xFFFFFFFF (two f16 NaNs -- unreachable by real data)
static __device__ __forceinline__ unsigned chkp(unsigned long long q) {
    return ((unsigned)q == 0xFFFFFFFFu) | ((unsigned)(q >> 32) == 0xFFFFFFFFu);
}
// zero any poison halves (rail: turns a liveness bug into bounded error)
static __device__ __forceinline__ unsigned long long sanq(unsigned long long q) {
    if ((unsigned)q == 0xFFFFFFFFu)         q &= 0xFFFFFFFF00000000ull;
    if ((unsigned)(q >> 32) == 0xFFFFFFFFu) q &= 0x00000000FFFFFFFFull;
    return q;
}

// ---------------- f32 -> f16 hi/lo conversion (8 elems) ----------------
static __device__ __forceinline__ void cvt8(const float* v, f16x8& hi, f16x8& lo)
{
#pragma unroll
    for (int i = 0; i < 8; i++) {
        _Float16 h = (_Float16)v[i];
        hi[i] = h;
        lo[i] = (_Float16)((v[i] - (float)h) * 2048.f);
    }
}
static __device__ __forceinline__ void cvt_pair8(float4 a, float4 b,
                                                 f16x8& hi, f16x8& lo)
{
    float v[8] = {a.x, a.y, a.z, a.w, b.x, b.y, b.z, b.w};
    cvt8(v, hi, lo);
}

// LDS A-tile for GEMMs: [2 bufs][64 rows][40 u16] per plane
#define AROW 40

// ---------------- layer-0 dual GEMM: fused embedding, LDS-staged A, poison init ----------------
__global__ __launch_bounds__(256) void gemm_l0_embed_dual(
    const int* __restrict__ tok, const int* __restrict__ pos,
    const float* __restrict__ wW, const float* __restrict__ pW,
    const float* __restrict__ W0, const float* __restrict__ b0, float* __restrict__ C0,
    const float* __restrict__ W1, const float* __restrict__ b1, float* __restrict__ C1,
    unsigned int* __restrict__ poison, int poison_words)
{
    {
        int nthreads = gridDim.x * gridDim.y * 256;
        int gtid = (blockIdx.y * gridDim.x + blockIdx.x) * 256 + threadIdx.x;
        for (int i = gtid; i < poison_words; i += nthreads) poison[i] = 0xFFFFFFFFu;
    }

    int half = gridDim.x >> 1;
    int sel = blockIdx.x >= half;
    int bx = blockIdx.x - (sel ? half : 0);
    const float* W = sel ? W1 : W0;
    const float* bias = sel ? b1 : b0;
    float* C = sel ? C1 : C0;

    int tid = threadIdx.x;
    int wv = tid >> 6, l = tid & 63;
    int lm = l & 15, lk = l >> 4;
    int rs = bx * 64 + wv * 16;          // < 1600 always
    int n0 = blockIdx.y * 64;

    __shared__ __attribute__((aligned(16))) unsigned short AhiS[2][64 * AROW];
    __shared__ __attribute__((aligned(16))) unsigned short AloS[2][64 * AROW];

    int sr = tid >> 2, sc = (tid & 3) * 8;
    int t_ = tok[n0 + sr], p_ = pos[n0 + sr];

    const float* wrow = W + (size_t)(rs + lm) * DIN0;

    f32x4 accH[4], accX[4];
#pragma unroll
    for (int ct = 0; ct < 4; ct++) {
        accH[ct] = {0.f, 0.f, 0.f, 0.f};
        accX[ct] = {0.f, 0.f, 0.f, 0.f};
    }

    float a8[8];
#pragma unroll
    for (int e = 0; e < 8; e++) {
        int k = sc + e;
        a8[e] = (k < 100) ? wW[t_ * 100 + k]
              : (k < DIN0) ? pW[p_ * 50 + (k - 100)] : 0.f;
    }
    float w8[8];
#pragma unroll
    for (int e = 0; e < 8; e++) {
        int k = lk * 8 + e;
        w8[e] = (k < DIN0) ? wrow[k] : 0.f;
    }
    {
        f16x8 h, lo2; cvt8(a8, h, lo2);
        *(f16x8*)&AhiS[0][sr * AROW + sc] = h;
        *(f16x8*)&AloS[0][sr * AROW + sc] = lo2;
    }

    const int nkt = 5;                   // KP0 = 160
    for (int kt = 0; kt < nkt; kt++) {
        __syncthreads();
        bool more = (kt + 1 < nkt);
        float a8n[8], w8n[8];
        if (more) {
            int kb = (kt + 1) << 5;
#pragma unroll
            for (int e = 0; e < 8; e++) {
                int k = kb + sc + e;
                a8n[e] = (k < 100) ? wW[t_ * 100 + k]
                       : (k < DIN0) ? pW[p_ * 50 + (k - 100)] : 0.f;
            }
#pragma unroll
            for (int e = 0; e < 8; e++) {
                int k = kb + lk * 8 + e;
                w8n[e] = (k < DIN0) ? wrow[k] : 0.f;
            }
        }
        f16x8 wh, wl; cvt8(w8, wh, wl);
        int buf = kt & 1;
#pragma unroll
        for (int ct = 0; ct < 4; ct++) {
            f16x8 ah = *(const f16x8*)&AhiS[buf][(ct * 16 + lm) * AROW + lk * 8];
            f16x8 al = *(const f16x8*)&AloS[buf][(ct * 16 + lm) * AROW + lk * 8];
            accH[ct] = __builtin_amdgcn_mfma_f32_16x16x32_f16(wh, ah, accH[ct], 0, 0, 0);
            accX[ct] = __builtin_amdgcn_mfma_f32_16x16x32_f16(wh, al, accX[ct], 0, 0, 0);
            accX[ct] = __builtin_amdgcn_mfma_f32_16x16x32_f16(wl, ah, accX[ct], 0, 0, 0);
        }
        if (more) {
            f16x8 h, lo2; cvt8(a8n, h, lo2);
            *(f16x8*)&AhiS[buf ^ 1][sr * AROW + sc] = h;
            *(f16x8*)&AloS[buf ^ 1][sr * AROW + sc] = lo2;
#pragma unroll
            for (int e = 0; e < 8; e++) w8[e] = w8n[e];
        }
    }

    float4 bv = *(const float4*)&bias[rs + lk * 4];
#pragma unroll
    for (int ct = 0; ct < 4; ct++) {
        f32x4 v = accH[ct] + accX[ct] * (1.f / 2048.f);
        float4 o;
        o.x = v[0] + bv.x; o.y = v[1] + bv.y; o.z = v[2] + bv.z; o.w = v[3] + bv.w;
        *(float4*)&C[(size_t)(n0 + ct * 16 + lm) * G4 + rs + lk * 4] = o;
    }
}

// ---------------- dual MFMA NT GEMM, LDS-staged shared A (+ optional re-poison) ----------------
__global__ __launch_bounds__(256) void gemm_nt_mfma_dual(
    const float* __restrict__ A,
    const float* __restrict__ W0, const float* __restrict__ b0, float* __restrict__ C0,
    const float* __restrict__ W1, const float* __restrict__ b1, float* __restrict__ C1,
    int K, int R,
    unsigned int* __restrict__ poison, int poison_words)
{
    if (poison) {
        int nthreads = gridDim.x * gridDim.y * 256;
        int gtid = (blockIdx.y * gridDim.x + blockIdx.x) * 256 + threadIdx.x;
        for (int i = gtid; i < poison_words; i += nthreads) poison[i] = 0xFFFFFFFFu;
    }

    int half = gridDim.x >> 1;
    int sel = blockIdx.x >= half;
    int bx = blockIdx.x - (sel ? half : 0);
    const float* W = sel ? W1 : W0;
    const float* bias = sel ? b1 : b0;
    float* C = sel ? C1 : C0;

    int tid = threadIdx.x;
    int wv = tid >> 6, l = tid & 63;
    int lm = l & 15, lk = l >> 4;
    int rs = bx * 64 + wv * 16;
    bool active = (rs < R);
    int n0 = blockIdx.y * 64;

    __shared__ __attribute__((aligned(16))) unsigned short AhiS[2][64 * AROW];
    __shared__ __attribute__((aligned(16))) unsigned short AloS[2][64 * AROW];

    int sr = tid >> 2, sc = (tid & 3) * 8;
    const float* arow_g = A + (size_t)(n0 + sr) * K + sc;
    const float* wrow = W + (size_t)((active ? rs : 0) + lm) * K + lk * 8;

    f32x4 accH[4], accX[4];
#pragma unroll
    for (int ct = 0; ct < 4; ct++) {
        accH[ct] = {0.f, 0.f, 0.f, 0.f};
        accX[ct] = {0.f, 0.f, 0.f, 0.f};
    }

    float a8[8];
    *(float4*)a8       = *(const float4*)arow_g;
    *(float4*)(a8 + 4) = *(const float4*)(arow_g + 4);
    float4 wA = {0,0,0,0}, wB = {0,0,0,0};
    if (active) { wA = *(const float4*)wrow; wB = *(const float4*)(wrow + 4); }
    {
        f16x8 h, lo2; cvt8(a8, h, lo2);
        *(f16x8*)&AhiS[0][sr * AROW + sc] = h;
        *(f16x8*)&AloS[0][sr * AROW + sc] = lo2;
    }

    int nkt = K >> 5;
    for (int kt = 0; kt < nkt; kt++) {
        __syncthreads();
        bool more = (kt + 1 < nkt);
        float a8n[8]; float4 wAn = {0,0,0,0}, wBn = {0,0,0,0};
        if (more) {
            int kb = (kt + 1) << 5;
            *(float4*)a8n       = *(const float4*)(arow_g + kb);
            *(float4*)(a8n + 4) = *(const float4*)(arow_g + kb + 4);
            if (active) {
                wAn = *(const float4*)(wrow + kb);
                wBn = *(const float4*)(wrow + kb + 4);
            }
        }
        if (active) {
            f16x8 wh, wl; cvt_pair8(wA, wB, wh, wl);
            int buf = kt & 1;
#pragma unroll
            for (int ct = 0; ct < 4; ct++) {
                f16x8 ah = *(const f16x8*)&AhiS[buf][(ct * 16 + lm) * AROW + lk * 8];
                f16x8 al = *(const f16x8*)&AloS[buf][(ct * 16 + lm) * AROW + lk * 8];
                accH[ct] = __builtin_amdgcn_mfma_f32_16x16x32_f16(wh, ah, accH[ct], 0, 0, 0);
                accX[ct] = __builtin_amdgcn_mfma_f32_16x16x32_f16(wh, al, accX[ct], 0, 0, 0);
                accX[ct] = __builtin_amdgcn_mfma_f32_16x16x32_f16(wl, ah, accX[ct], 0, 0, 0);
            }
        }
        if (more) {
            f16x8 h, lo2; cvt8(a8n, h, lo2);
            *(f16x8*)&AhiS[(kt & 1) ^ 1][sr * AROW + sc] = h;
            *(f16x8*)&AloS[(kt & 1) ^ 1][sr * AROW + sc] = lo2;
            wA = wAn; wB = wBn;
        }
    }

    if (!active) return;
    float4 bv = *(const float4*)&bias[rs + lk * 4];
#pragma unroll
    for (int ct = 0; ct < 4; ct++) {
        f32x4 v = accH[ct] + accX[ct] * (1.f / 2048.f);
        float4 o;
        o.x = v[0] + bv.x; o.y = v[1] + bv.y; o.z = v[2] + bv.z; o.w = v[3] + bv.w;
        *(float4*)&C[(size_t)(n0 + ct * 16 + lm) * R + rs + lk * 4] = o;
    }
}

// ---------------- LSTM recurrence: 4-wave WGs, shared-poll via LDS ----------------
// 25 WGs/dir x 256 threads (4 waves). Wave wv owns hidden units j0w+4*wv..+3 (one
// 16x16 D-tile, same structure as the verified 1-wave kernel). The h B-fragments
// are IDENTICAL across waves -> polled ONCE per WG, wave-partitioned over the 13
// k-tiles (wave w polls kts {0-3},{4-6},{7-9},{10-12}), staged into LDS, shared.
// Cuts poll traffic 4x (50 WGs vs 200) and per-wave poll size ~3x.
// Rendezvous: rdy[4] flags + 2-barrier rounds; `all` read between the barriers is
// uniform -> uniform exit; force-write+sanitize at guard cap keeps rounds lockstep
// and bounded (never NaN, never unbounded spin).
// Exchange format/publish identical to round-9 (producers: relaxed agent u32s).
__global__ __launch_bounds__(256, 1) void lstm_layer_kernel(
    const float* __restrict__ Gf, const float* __restrict__ Gb,
    const float* __restrict__ Wf, const float* __restrict__ Wb,
    float* __restrict__ hbuf,          // [B][S][800] fp32 for downstream kernels
    unsigned short* __restrict__ exhi, // f16 hi plane, frag layout [dir][s][kt][64][8]
    unsigned short* __restrict__ exlo) // f16 lo plane (x2048)
{
    const int dir = blockIdx.x / LWGS;
    const int wg  = blockIdx.x % LWGS;
    const int j0w = wg * 16;            // WG's hidden base
    const float* __restrict__ G = dir ? Gb : Gf;
    const float* __restrict__ W = dir ? Wb : Wf;

    const int tid = threadIdx.x;
    const int wv  = tid >> 6;           // wave 0..3
    const int l   = tid & 63;
    const int b   = l & 15;
    const int hi4 = l >> 4;
    const int j0  = j0w + wv * 4;       // this wave's 4 hidden units

    __shared__ __attribute__((aligned(16))) unsigned short ahi[4][13 * 64 * 8];
    __shared__ __attribute__((aligned(16))) unsigned short alo[4][13 * 64 * 8];
    __shared__ __attribute__((aligned(16))) unsigned short hshhi[13 * 64 * 8];
    __shared__ __attribute__((aligned(16))) unsigned short hshlo[13 * 64 * 8];
    __shared__ float gl[4][16 * 17];
    __shared__ int rdy[4];

    // ---- one-time: weights -> f16 hi/lo A-fragments in LDS (per wave) ----
    {
        const int g = b >> 2, jj = b & 3;
        const float* wrow = W + (size_t)(g * HH + j0 + jj) * HH;
        for (int kt = 0; kt < 13; kt++) {
            for (int e = 0; e < 8; e++) {
                int k = kt * 32 + hi4 * 8 + e;
                float w = (k < HH) ? wrow[k] : 0.f;
                _Float16 wh = (_Float16)w;
                _Float16 wl = (_Float16)((w - (float)wh) * 2048.f);
                ahi[wv][(kt * 64 + l) * 8 + e] = __builtin_bit_cast(unsigned short, wh);
                alo[wv][(kt * 64 + l) * 8 + e] = __builtin_bit_cast(unsigned short, wl);
            }
        }
    }
    if (tid < 4) rdy[tid] = 0;
    __syncthreads();

    // cell role: thread -> (hidden ju, batch b2)
    const int ju = tid >> 4;            // 0..15
    const int b2 = tid & 15;
    float c_reg = 0.f;

    const int ktA4[4] = {0, 4, 7, 10};
    const int ktB4[4] = {4, 7, 10, 13};
    const int ktA = ktA4[wv], ktB = ktB4[wv];

    unsigned short* exh_d = exhi + (size_t)dir * 100 * 13 * 512;
    unsigned short* exl_d = exlo + (size_t)dir * 100 * 13 * 512;

    for (int s = 0; s < SS; s++) {
        const int time = dir ? (SS - 1 - s) : s;
        f32x4 gpre = *(const f32x4*)&G[(size_t)(b * SS + time) * G4 + hi4 * HH + j0];

        f32x4 acc;
        if (s > 0) {
            const unsigned long long* pbh =
                (const unsigned long long*)(exh_d + (size_t)(s - 1) * 13 * 512);
            const unsigned long long* pbl =
                (const unsigned long long*)(exl_d + (size_t)(s - 1) * 13 * 512);
            unsigned long long vh[4][2], vl[4][2];
            bool mine = false;
            for (int guard = 0; ; guard++) {
                if (!mine) {
                    unsigned bad = 0;
                    for (int kt = ktA; kt < ktB; kt++) {
                        int ki = kt - ktA;
                        if (kt == 12 && hi4 >= 2) {   // pad k=400..415: never written
                            vh[ki][0] = vh[ki][1] = 0ull;
                            vl[ki][0] = vl[ki][1] = 0ull;
                            continue;
                        }
                        size_t q = (size_t)(kt * 64 + l) * 2;
                        vh[ki][0] = __hip_atomic_load(pbh + q,     __ATOMIC_RELAXED, __HIP_MEMORY_SCOPE_AGENT);
                        vh[ki][1] = __hip_atomic_load(pbh + q + 1, __ATOMIC_RELAXED, __HIP_MEMORY_SCOPE_AGENT);
                        vl[ki][0] = __hip_atomic_load(pbl + q,     __ATOMIC_RELAXED, __HIP_MEMORY_SCOPE_AGENT);
                        vl[ki][1] = __hip_atomic_load(pbl + q + 1, __ATOMIC_RELAXED, __HIP_MEMORY_SCOPE_AGENT);
                        bad |= chkp(vh[ki][0]) | chkp(vh[ki][1])
                             | chkp(vl[ki][0]) | chkp(vl[ki][1]);
                    }
                    bool force = (guard >= (1 << 13));
                    if ((__ballot(bad != 0) == 0ull) || force) {
                        for (int kt = ktA; kt < ktB; kt++) {
                            int ki = kt - ktA;
                            if (force) {
                                vh[ki][0] = sanq(vh[ki][0]); vh[ki][1] = sanq(vh[ki][1]);
                                vl[ki][0] = sanq(vl[ki][0]); vl[ki][1] = sanq(vl[ki][1]);
                            }
                            int base = (kt * 64 + l) * 8;
                            *(unsigned long long*)&hshhi[base]     = vh[ki][0];
                            *(unsigned long long*)&hshhi[base + 4] = vh[ki][1];
                            *(unsigned long long*)&hshlo[base]     = vl[ki][0];
                            *(unsigned long long*)&hshlo[base + 4] = vl[ki][1];
                        }
                        mine = true;
                        if (l == 0) rdy[wv] = 1;
                    }
                }
                __syncthreads();
                int all = rdy[0] & rdy[1] & rdy[2] & rdy[3];
                __syncthreads();
                if (all) break;
                __builtin_amdgcn_s_sleep(1);
            }
            if (tid < 4) rdy[tid] = 0;    // reset for next step (ordered by later barriers)

            f32x4 aHH = gpre;
            f32x4 aHL = {0.f, 0.f, 0.f, 0.f};
            f32x4 aLH = {0.f, 0.f, 0.f, 0.f};
#pragma unroll
            for (int kt = 0; kt < 13; kt++) {
                int base = (kt * 64 + l) * 8;
                f16x8 bhv = *(const f16x8*)&hshhi[base];
                f16x8 blv = *(const f16x8*)&hshlo[base];
                f16x8 wh = *(const f16x8*)&ahi[wv][base];
                f16x8 wl = *(const f16x8*)&alo[wv][base];
                aHH = __builtin_amdgcn_mfma_f32_16x16x32_f16(wh, bhv, aHH, 0, 0, 0);
                aHL = __builtin_amdgcn_mfma_f32_16x16x32_f16(wh, blv, aHL, 0, 0, 0);
                aLH = __builtin_amdgcn_mfma_f32_16x16x32_f16(wl, bhv, aLH, 0, 0, 0);
            }
            acc = aHH + (aHL + aLH) * (1.f / 2048.f);
        } else {
            acc = gpre;   // h(-1) = 0
        }

        // D lane l holds rows 4*hi4+q (gate hi4, hidden j0+q), col b
#pragma unroll
        for (int q = 0; q < 4; q++) gl[wv][(4 * hi4 + q) * 17 + b] = acc[q];
        __syncthreads();

        const int wq = ju >> 2, jj = ju & 3;
        float gi = gl[wq][( 0 + jj) * 17 + b2];
        float gf = gl[wq][( 4 + jj) * 17 + b2];
        float gg = gl[wq][( 8 + jj) * 17 + b2];
        float go = gl[wq][(12 + jj) * 17 + b2];
        __syncthreads();

        float si = 1.f / (1.f + expf(-gi));
        float sf = 1.f / (1.f + expf(-gf));
        float tg = tanhf(gg);
        float so = 1.f / (1.f + expf(-go));
        float c  = sf * c_reg + si * tg;
        c_reg = c;
        float h  = so * tanhf(c);

        if (s < SS - 1) {
            _Float16 hh = (_Float16)h;
            _Float16 hl = (_Float16)((h - (float)hh) * 2048.f);
            unsigned uh = __builtin_bit_cast(unsigned short, hh);
            unsigned ul = __builtin_bit_cast(unsigned short, hl);
            unsigned ph = uh | (((unsigned)__shfl_down((int)uh, 16)) << 16);
            unsigned pl = ul | (((unsigned)__shfl_down((int)ul, 16)) << 16);
            if ((ju & 1) == 0) {          // even ju stores the (k0, k0+1) pair
                int k0 = j0w + ju;
                int kt = k0 >> 5, ko = k0 & 31;
                int lg = ko >> 3, e = ko & 7;
                size_t u16idx = ((size_t)(s * 13 + kt) * 64 + (lg * 16 + b2)) * 8 + e;
                __hip_atomic_store((unsigned*)(exh_d + u16idx), ph,
                                   __ATOMIC_RELAXED, __HIP_MEMORY_SCOPE_AGENT);
                __hip_atomic_store((unsigned*)(exl_d + u16idx), pl,
                                   __ATOMIC_RELAXED, __HIP_MEMORY_SCOPE_AGENT);
            }
        }

        hbuf[(size_t)(b2 * SS + time) * H2 + dir * HH + j0w + ju] = h;
    }
}

// ---------------- attention scores + fused row softmax/table/preds/nll ----------------
#define ITILE 11
__global__ __launch_bounds__(256) void attn_scores_softmax_kernel(
    const float* __restrict__ ua, const float* __restrict__ wa,
    const float* __restrict__ va, const float* __restrict__ out2,
    const int* __restrict__ head, float* __restrict__ outb,
    float* __restrict__ nll)
{
    int b  = blockIdx.x / 9;
    int i0 = (blockIdx.x % 9) * ITILE;
    int tid = threadIdx.x;
    __shared__ float ua_t[100][101];
    __shared__ float wa_t[ITILE][102];
    __shared__ float sacc[ITILE][101];
    __shared__ float va_t[100];
    __shared__ float h0[100];

    for (int p = tid; p < ITILE * 101; p += 256) ((float*)sacc)[p] = 0.f;
    if (tid < 100) h0[tid] = out2[(size_t)(b * SS + tid) * H2];

    for (int ht = 0; ht < 8; ht++) {
        int hh0 = ht * 100;
        __syncthreads();
        for (int p = tid; p < 100 * 100; p += 256) {
            int j = p / 100, hh = p % 100;
            ua_t[j][hh] = ua[(size_t)(b * SS + j) * H2 + hh0 + hh];
        }
        for (int p = tid; p < ITILE * 100; p += 256) {
            int il = p / 100, hh = p % 100;
            wa_t[il][hh] = wa[(size_t)(b * SS + i0 + il + 1) * H2 + hh0 + hh];
        }
        if (tid < 100) va_t[tid] = va[hh0 + tid];
        __syncthreads();
        for (int p = tid; p < ITILE * 100; p += 256) {
            int il = p / 100, j = p % 100;
            float acc = 0.f;
#pragma unroll 4
            for (int hh = 0; hh < 100; hh++) {
                float x = ua_t[j][hh] + wa_t[il][hh];
                float z = __expf(2.f * x);
                float th = 1.f - 2.f * __builtin_amdgcn_rcpf(z + 1.f);
                acc = fmaf(th, va_t[hh], acc);
            }
            sacc[il][j] += acc;
        }
    }
    __syncthreads();

    int wv = tid >> 6, ln = tid & 63;
    for (int il = wv; il < ITILE; il += 4) {
        int i = i0 + il;                 // 0..98
        int bi = b * 99 + i;
        float h_t = h0[i + 1];
        int j1 = ln, j2 = ln + 64;
        float s1 = sacc[il][j1];
        if (h0[j1] == h_t) s1 = -10000.0f;
        float s2 = -1e30f;
        if (j2 < 100) {
            s2 = sacc[il][j2];
            if (h0[j2] == h_t) s2 = -10000.0f;
        }
        float v = s1; int vi = j1;
        if (s2 > v) { v = s2; vi = j2; }          // j1 < j2: ties keep j1
        for (int k = 32; k >= 1; k >>= 1) {
            float vo = __shfl_xor(v, k);
            int   io = __shfl_xor(vi, k);
            if (vo > v || (vo == v && io < vi)) { v = vo; vi = io; }
        }
        float m = v; int amax = vi;
        float e1 = __expf(s1 - m);
        float e2 = (j2 < 100) ? __expf(s2 - m) : 0.f;
        float sum = e1 + e2;
        for (int k = 32; k >= 1; k >>= 1) sum += __shfl_xor(sum, k);
        float inv = 1.f / sum;
        outb[1 + 1584 + (size_t)bi * 100 + j1] = e1 * inv;
        if (j2 < 100) outb[1 + 1584 + (size_t)bi * 100 + j2] = e2 * inv;
        if (ln == 0) {
            outb[1 + bi] = (float)amax;
            int gold = head[b * SS + i + 1];
            bool valid = (gold != -1);
            int gc = gold < 0 ? 0 : (gold > 99 ? 99 : gold);
            float sgc = sacc[il][gc];
            if (h0[gc] == h_t) sgc = -10000.0f;
            nll[bi] = valid ? -(sgc - m - logf(sum)) : 0.f;
        }
    }
}

// ---------------- final loss reduction ----------------
__global__ __launch_bounds__(128) void loss_kernel(
    const float* __restrict__ nll, const int* __restrict__ head,
    float* __restrict__ outb)
{
    __shared__ float red[128];
    int tid = threadIdx.x;
    float contrib = 0.f;
    if (tid < 99) {
        int i = tid;
        float tot = 0.f; int cv = 0;
        for (int b = 0; b < BB; b++) {
            tot += nll[b * 99 + i];
            cv += (head[b * SS + i + 1] != -1) ? 1 : 0;
        }
        int denom = cv > 0 ? cv : 1;
        contrib = tot / (float)denom;
    }
    red[tid] = contrib;
    __syncthreads();
    for (int off = 64; off >= 1; off >>= 1) {
        if (tid < off) red[tid] += red[tid + off];
        __syncthreads();
    }
    if (tid == 0) outb[0] = red[0];
}

// ---------------- launch (7 nodes) ----------------
extern "C" void kernel_launch(void* const* d_in, const int* in_sizes, int n_in,
                              void* d_out, int out_size, void* d_ws, size_t ws_size,
                              hipStream_t stream) {
    const int*   tok     = (const int*)d_in[0];
    const int*   pos     = (const int*)d_in[1];
    const int*   head    = (const int*)d_in[2];
    const float* word_W  = (const float*)d_in[3];
    const float* pos_W   = (const float*)d_in[4];
    const float* l0f_Wih = (const float*)d_in[5];
    const float* l0f_Whh = (const float*)d_in[6];
    const float* l0f_b   = (const float*)d_in[7];
    const float* l0b_Wih = (const float*)d_in[8];
    const float* l0b_Whh = (const float*)d_in[9];
    const float* l0b_b   = (const float*)d_in[10];
    const float* l1f_Wih = (const float*)d_in[11];
    const float* l1f_Whh = (const float*)d_in[12];
    const float* l1f_b   = (const float*)d_in[13];
    const float* l1b_Wih = (const float*)d_in[14];
    const float* l1b_Whh = (const float*)d_in[15];
    const float* l1b_b   = (const float*)d_in[16];
    const float* ua_W    = (const float*)d_in[17];
    const float* ua_b    = (const float*)d_in[18];
    const float* wa_W    = (const float*)d_in[19];
    const float* wa_b    = (const float*)d_in[20];
    const float* va_W    = (const float*)d_in[21];

    float* ws   = (float*)d_ws;
    float* gf   = ws + OFF_GF;   // g0f / g1f / ua
    float* gb   = ws + OFF_GB;   // g0b / g1b / wa
    float* h1   = ws + OFF_H1;
    float* out2 = ws + OFF_OUT2;
    float* nllb = ws + OFF_NLL;
    unsigned short* exhi = (unsigned short*)(ws + OFF_EXH);
    unsigned short* exlo = exhi + EX_U16_PER_PLANE;
    float* outf = (float*)d_out;

    // layer-0 projections: fused embedding + LDS-staged A + poison init
    gemm_l0_embed_dual<<<dim3(50, 25), 256, 0, stream>>>(
        tok, pos, word_W, pos_W,
        l0f_Wih, l0f_b, gf, l0b_Wih, l0b_b, gb,
        (unsigned int*)exhi, (int)EX_U16_PER_PLANE);
    // layer-0 recurrence (4-wave WGs, shared poll)
    lstm_layer_kernel<<<dim3(2 * LWGS), 256, 0, stream>>>(
        gf, gb, l0f_Whh, l0b_Whh, h1, exhi, exlo);
    // layer-1 projections (K=800) + exchange re-poison
    gemm_nt_mfma_dual<<<dim3(50, 25), 256, 0, stream>>>(
        h1, l1f_Wih, l1f_b, gf, l1b_Wih, l1b_b, gb, H2, G4,
        (unsigned int*)exhi, (int)EX_U16_PER_PLANE);
    // layer-1 recurrence
    lstm_layer_kernel<<<dim3(2 * LWGS), 256, 0, stream>>>(
        gf, gb, l1f_Whh, l1b_Whh, out2, exhi, exlo);
    // attention projections (K=800, R=800)
    gemm_nt_mfma_dual<<<dim3(26, 25), 256, 0, stream>>>(
        out2, ua_W, ua_b, gf, wa_W, wa_b, gb, H2, H2, nullptr, 0);
    // scores + fused softmax/table/preds/nll
    attn_scores_softmax_kernel<<<dim3(16 * 9), 256, 0, stream>>>(
        gf, gb, va_W, out2, head, outf, nllb);
    // final loss
    loss_kernel<<<dim3(1), 128, 0, stream>>>(nllb, head, outf);
}

// Round 13
// 1223.804 us; speedup vs baseline: 1.5437x; 1.5437x over previous
//
#include <hip/hip_runtime.h>

// ---------------- problem constants ----------------
#define BB 16
#define SS 100
#define HH 400      // hidden per direction
#define H2 800
#define G4 1600     // 4*H gate rows
#define DIN0 150    // WE+PE
#define KP0 160     // padded layer-0 K (150 -> 160, K%32==0)

// ---------------- workspace layout (float offsets) ----------------
#define OFF_GF   240000ULL     // 2,560,000 (g0f / g1f / ua)
#define OFF_GB   2800000ULL    // 2,560,000 (g0b / g1b / wa)
#define OFF_H1   5360000ULL    // 1,280,000
#define OFF_OUT2 6640000ULL    // 1,280,000
#define OFF_NLL  8078400ULL    // 1,600
#define OFF_EXH  8081600ULL    // u16 exchange planes (exhi then exlo, contiguous)
#define EX_U16_PER_PLANE 1331200ULL   // 2 dir * 100 steps * 13 kt * 64 * 8

typedef _Float16 f16x8 __attribute__((ext_vector_type(8)));
typedef float    f32x4 __attribute__((ext_vector_type(4)));
typedef unsigned long long u64x2 __attribute__((ext_vector_type(2)));

// poison check: u32 half == 0xFFFFFFFF (two f16 NaNs -- unreachable by real data)
static __device__ __forceinline__ unsigned chkp(unsigned long long q) {
    return ((unsigned)q == 0xFFFFFFFFu) | ((unsigned)(q >> 32) == 0xFFFFFFFFu);
}
// zero any poison halves (rail: turns a liveness bug into bounded error)
static __device__ __forceinline__ unsigned long long sanq(unsigned long long q) {
    if ((unsigned)q == 0xFFFFFFFFu)         q &= 0xFFFFFFFF00000000ull;
    if ((unsigned)(q >> 32) == 0xFFFFFFFFu) q &= 0x00000000FFFFFFFFull;
    return q;
}

// ---------------- f32 -> f16 hi/lo conversion (8 elems) ----------------
static __device__ __forceinline__ void cvt8(const float* v, f16x8& hi, f16x8& lo)
{
#pragma unroll
    for (int i = 0; i < 8; i++) {
        _Float16 h = (_Float16)v[i];
        hi[i] = h;
        lo[i] = (_Float16)((v[i] - (float)h) * 2048.f);
    }
}
static __device__ __forceinline__ void cvt_pair8(float4 a, float4 b,
                                                 f16x8& hi, f16x8& lo)
{
    float v[8] = {a.x, a.y, a.z, a.w, b.x, b.y, b.z, b.w};
    cvt8(v, hi, lo);
}

// LDS A-tile for GEMMs: [2 bufs][64 rows][40 u16] per plane
#define AROW 40

// ---------------- layer-0 dual GEMM: fused embedding, LDS-staged A, poison init ----------------
__global__ __launch_bounds__(256) void gemm_l0_embed_dual(
    const int* __restrict__ tok, const int* __restrict__ pos,
    const float* __restrict__ wW, const float* __restrict__ pW,
    const float* __restrict__ W0, const float* __restrict__ b0, float* __restrict__ C0,
    const float* __restrict__ W1, const float* __restrict__ b1, float* __restrict__ C1,
    unsigned int* __restrict__ poison, int poison_words)
{
    {
        int nthreads = gridDim.x * gridDim.y * 256;
        int gtid = (blockIdx.y * gridDim.x + blockIdx.x) * 256 + threadIdx.x;
        for (int i = gtid; i < poison_words; i += nthreads) poison[i] = 0xFFFFFFFFu;
    }

    int half = gridDim.x >> 1;
    int sel = blockIdx.x >= half;
    int bx = blockIdx.x - (sel ? half : 0);
    const float* W = sel ? W1 : W0;
    const float* bias = sel ? b1 : b0;
    float* C = sel ? C1 : C0;

    int tid = threadIdx.x;
    int wv = tid >> 6, l = tid & 63;
    int lm = l & 15, lk = l >> 4;
    int rs = bx * 64 + wv * 16;          // < 1600 always
    int n0 = blockIdx.y * 64;

    __shared__ __attribute__((aligned(16))) unsigned short AhiS[2][64 * AROW];
    __shared__ __attribute__((aligned(16))) unsigned short AloS[2][64 * AROW];

    int sr = tid >> 2, sc = (tid & 3) * 8;
    int t_ = tok[n0 + sr], p_ = pos[n0 + sr];

    const float* wrow = W + (size_t)(rs + lm) * DIN0;

    f32x4 accH[4], accX[4];
#pragma unroll
    for (int ct = 0; ct < 4; ct++) {
        accH[ct] = {0.f, 0.f, 0.f, 0.f};
        accX[ct] = {0.f, 0.f, 0.f, 0.f};
    }

    float a8[8];
#pragma unroll
    for (int e = 0; e < 8; e++) {
        int k = sc + e;
        a8[e] = (k < 100) ? wW[t_ * 100 + k]
              : (k < DIN0) ? pW[p_ * 50 + (k - 100)] : 0.f;
    }
    float w8[8];
#pragma unroll
    for (int e = 0; e < 8; e++) {
        int k = lk * 8 + e;
        w8[e] = (k < DIN0) ? wrow[k] : 0.f;
    }
    {
        f16x8 h, lo2; cvt8(a8, h, lo2);
        *(f16x8*)&AhiS[0][sr * AROW + sc] = h;
        *(f16x8*)&AloS[0][sr * AROW + sc] = lo2;
    }

    const int nkt = 5;                   // KP0 = 160
    for (int kt = 0; kt < nkt; kt++) {
        __syncthreads();
        bool more = (kt + 1 < nkt);
        float a8n[8], w8n[8];
        if (more) {
            int kb = (kt + 1) << 5;
#pragma unroll
            for (int e = 0; e < 8; e++) {
                int k = kb + sc + e;
                a8n[e] = (k < 100) ? wW[t_ * 100 + k]
                       : (k < DIN0) ? pW[p_ * 50 + (k - 100)] : 0.f;
            }
#pragma unroll
            for (int e = 0; e < 8; e++) {
                int k = kb + lk * 8 + e;
                w8n[e] = (k < DIN0) ? wrow[k] : 0.f;
            }
        }
        f16x8 wh, wl; cvt8(w8, wh, wl);
        int buf = kt & 1;
#pragma unroll
        for (int ct = 0; ct < 4; ct++) {
            f16x8 ah = *(const f16x8*)&AhiS[buf][(ct * 16 + lm) * AROW + lk * 8];
            f16x8 al = *(const f16x8*)&AloS[buf][(ct * 16 + lm) * AROW + lk * 8];
            accH[ct] = __builtin_amdgcn_mfma_f32_16x16x32_f16(wh, ah, accH[ct], 0, 0, 0);
            accX[ct] = __builtin_amdgcn_mfma_f32_16x16x32_f16(wh, al, accX[ct], 0, 0, 0);
            accX[ct] = __builtin_amdgcn_mfma_f32_16x16x32_f16(wl, ah, accX[ct], 0, 0, 0);
        }
        if (more) {
            f16x8 h, lo2; cvt8(a8n, h, lo2);
            *(f16x8*)&AhiS[buf ^ 1][sr * AROW + sc] = h;
            *(f16x8*)&AloS[buf ^ 1][sr * AROW + sc] = lo2;
#pragma unroll
            for (int e = 0; e < 8; e++) w8[e] = w8n[e];
        }
    }

    float4 bv = *(const float4*)&bias[rs + lk * 4];
#pragma unroll
    for (int ct = 0; ct < 4; ct++) {
        f32x4 v = accH[ct] + accX[ct] * (1.f / 2048.f);
        float4 o;
        o.x = v[0] + bv.x; o.y = v[1] + bv.y; o.z = v[2] + bv.z; o.w = v[3] + bv.w;
        *(float4*)&C[(size_t)(n0 + ct * 16 + lm) * G4 + rs + lk * 4] = o;
    }
}

// ---------------- dual MFMA NT GEMM, LDS-staged shared A (+ optional re-poison) ----------------
__global__ __launch_bounds__(256) void gemm_nt_mfma_dual(
    const float* __restrict__ A,
    const float* __restrict__ W0, const float* __restrict__ b0, float* __restrict__ C0,
    const float* __restrict__ W1, const float* __restrict__ b1, float* __restrict__ C1,
    int K, int R,
    unsigned int* __restrict__ poison, int poison_words)
{
    if (poison) {
        int nthreads = gridDim.x * gridDim.y * 256;
        int gtid = (blockIdx.y * gridDim.x + blockIdx.x) * 256 + threadIdx.x;
        for (int i = gtid; i < poison_words; i += nthreads) poison[i] = 0xFFFFFFFFu;
    }

    int half = gridDim.x >> 1;
    int sel = blockIdx.x >= half;
    int bx = blockIdx.x - (sel ? half : 0);
    const float* W = sel ? W1 : W0;
    const float* bias = sel ? b1 : b0;
    float* C = sel ? C1 : C0;

    int tid = threadIdx.x;
    int wv = tid >> 6, l = tid & 63;
    int lm = l & 15, lk = l >> 4;
    int rs = bx * 64 + wv * 16;
    bool active = (rs < R);
    int n0 = blockIdx.y * 64;

    __shared__ __attribute__((aligned(16))) unsigned short AhiS[2][64 * AROW];
    __shared__ __attribute__((aligned(16))) unsigned short AloS[2][64 * AROW];

    int sr = tid >> 2, sc = (tid & 3) * 8;
    const float* arow_g = A + (size_t)(n0 + sr) * K + sc;
    const float* wrow = W + (size_t)((active ? rs : 0) + lm) * K + lk * 8;

    f32x4 accH[4], accX[4];
#pragma unroll
    for (int ct = 0; ct < 4; ct++) {
        accH[ct] = {0.f, 0.f, 0.f, 0.f};
        accX[ct] = {0.f, 0.f, 0.f, 0.f};
    }

    float a8[8];
    *(float4*)a8       = *(const float4*)arow_g;
    *(float4*)(a8 + 4) = *(const float4*)(arow_g + 4);
    float4 wA = {0,0,0,0}, wB = {0,0,0,0};
    if (active) { wA = *(const float4*)wrow; wB = *(const float4*)(wrow + 4); }
    {
        f16x8 h, lo2; cvt8(a8, h, lo2);
        *(f16x8*)&AhiS[0][sr * AROW + sc] = h;
        *(f16x8*)&AloS[0][sr * AROW + sc] = lo2;
    }

    int nkt = K >> 5;
    for (int kt = 0; kt < nkt; kt++) {
        __syncthreads();
        bool more = (kt + 1 < nkt);
        float a8n[8]; float4 wAn = {0,0,0,0}, wBn = {0,0,0,0};
        if (more) {
            int kb = (kt + 1) << 5;
            *(float4*)a8n       = *(const float4*)(arow_g + kb);
            *(float4*)(a8n + 4) = *(const float4*)(arow_g + kb + 4);
            if (active) {
                wAn = *(const float4*)(wrow + kb);
                wBn = *(const float4*)(wrow + kb + 4);
            }
        }
        if (active) {
            f16x8 wh, wl; cvt_pair8(wA, wB, wh, wl);
            int buf = kt & 1;
#pragma unroll
            for (int ct = 0; ct < 4; ct++) {
                f16x8 ah = *(const f16x8*)&AhiS[buf][(ct * 16 + lm) * AROW + lk * 8];
                f16x8 al = *(const f16x8*)&AloS[buf][(ct * 16 + lm) * AROW + lk * 8];
                accH[ct] = __builtin_amdgcn_mfma_f32_16x16x32_f16(wh, ah, accH[ct], 0, 0, 0);
                accX[ct] = __builtin_amdgcn_mfma_f32_16x16x32_f16(wh, al, accX[ct], 0, 0, 0);
                accX[ct] = __builtin_amdgcn_mfma_f32_16x16x32_f16(wl, ah, accX[ct], 0, 0, 0);
            }
        }
        if (more) {
            f16x8 h, lo2; cvt8(a8n, h, lo2);
            *(f16x8*)&AhiS[(kt & 1) ^ 1][sr * AROW + sc] = h;
            *(f16x8*)&AloS[(kt & 1) ^ 1][sr * AROW + sc] = lo2;
            wA = wAn; wB = wBn;
        }
    }

    if (!active) return;
    float4 bv = *(const float4*)&bias[rs + lk * 4];
#pragma unroll
    for (int ct = 0; ct < 4; ct++) {
        f32x4 v = accH[ct] + accX[ct] * (1.f / 2048.f);
        float4 o;
        o.x = v[0] + bv.x; o.y = v[1] + bv.y; o.z = v[2] + bv.z; o.w = v[3] + bv.w;
        *(float4*)&C[(size_t)(n0 + ct * 16 + lm) * R + rs + lk * 4] = o;
    }
}

// ---------------- LSTM recurrence: MFMA f16 hi/lo, in-band poison sync ----------------
// ROUND-11 VERIFIED VERSION (~445 us/dispatch). Structural floor for this
// decomposition (rounds 6-12: counter barrier = poison = 445; 4-wave shared
// poll = 749). DO NOT TOUCH.
__global__ __launch_bounds__(64, 1) void lstm_layer_kernel(
    const float* __restrict__ Gf, const float* __restrict__ Gb,
    const float* __restrict__ Wf, const float* __restrict__ Wb,
    float* __restrict__ hbuf,          // [B][S][800] fp32 for downstream kernels
    unsigned short* __restrict__ exhi, // f16 hi plane, frag layout [dir][s][kt][64][8]
    unsigned short* __restrict__ exlo) // f16 lo plane (x2048)
{
    const int dir = blockIdx.x / 100;
    const int wg  = blockIdx.x % 100;
    const int j0  = wg * 4;
    const float* __restrict__ G = dir ? Gb : Gf;
    const float* __restrict__ W = dir ? Wb : Wf;

    const int l   = threadIdx.x;   // 0..63
    const int b   = l & 15;
    const int hi4 = l >> 4;

    __shared__ __attribute__((aligned(16))) unsigned short ahi[13 * 64 * 8];
    __shared__ __attribute__((aligned(16))) unsigned short alo[13 * 64 * 8];
    __shared__ float gl[16 * 17];

    {
        const int m = b;
        const int g = m >> 2, jj = m & 3;
        const float* wrow = W + (size_t)(g * HH + j0 + jj) * HH;
        for (int kt = 0; kt < 13; kt++) {
            for (int e = 0; e < 8; e++) {
                int k = kt * 32 + hi4 * 8 + e;
                float w = (k < HH) ? wrow[k] : 0.f;
                _Float16 wh = (_Float16)w;
                _Float16 wl = (_Float16)((w - (float)wh) * 2048.f);
                ahi[(kt * 64 + l) * 8 + e] = __builtin_bit_cast(unsigned short, wh);
                alo[(kt * 64 + l) * 8 + e] = __builtin_bit_cast(unsigned short, wl);
            }
        }
    }
    __syncthreads();

    float c_reg = 0.f;
    unsigned short* exh_d = exhi + (size_t)dir * 100 * 13 * 512;
    unsigned short* exl_d = exlo + (size_t)dir * 100 * 13 * 512;
    const int pad_lane = (hi4 >= 2);   // kt=12 k-range 400..415 for this lane

    for (int s = 0; s < SS; s++) {
        const int time = dir ? (SS - 1 - s) : s;
        f32x4 gpre = *(const f32x4*)&G[(size_t)(b * SS + time) * G4 + hi4 * HH + j0];

        f32x4 acc;
        if (s > 0) {
            const unsigned long long* pbh =
                (const unsigned long long*)(exh_d + (size_t)(s - 1) * 13 * 512);
            const unsigned long long* pbl =
                (const unsigned long long*)(exl_d + (size_t)(s - 1) * 13 * 512);
            u64x2 vh2[13], vl2[13];
            vh2[12] = {0ull, 0ull};
            vl2[12] = {0ull, 0ull};
            unsigned bad = 1;
            for (int guard = 0; guard < (1 << 13); guard++) {
                bad = 0;
#pragma unroll
                for (int kt = 0; kt < 12; kt++) {
                    size_t q = (size_t)(kt * 64 + l) * 2;
                    vh2[kt][0] = __hip_atomic_load(pbh + q,     __ATOMIC_RELAXED, __HIP_MEMORY_SCOPE_AGENT);
                    vh2[kt][1] = __hip_atomic_load(pbh + q + 1, __ATOMIC_RELAXED, __HIP_MEMORY_SCOPE_AGENT);
                    vl2[kt][0] = __hip_atomic_load(pbl + q,     __ATOMIC_RELAXED, __HIP_MEMORY_SCOPE_AGENT);
                    vl2[kt][1] = __hip_atomic_load(pbl + q + 1, __ATOMIC_RELAXED, __HIP_MEMORY_SCOPE_AGENT);
                }
                if (!pad_lane) {
                    size_t q = (size_t)(12 * 64 + l) * 2;
                    vh2[12][0] = __hip_atomic_load(pbh + q,     __ATOMIC_RELAXED, __HIP_MEMORY_SCOPE_AGENT);
                    vh2[12][1] = __hip_atomic_load(pbh + q + 1, __ATOMIC_RELAXED, __HIP_MEMORY_SCOPE_AGENT);
                    vl2[12][0] = __hip_atomic_load(pbl + q,     __ATOMIC_RELAXED, __HIP_MEMORY_SCOPE_AGENT);
                    vl2[12][1] = __hip_atomic_load(pbl + q + 1, __ATOMIC_RELAXED, __HIP_MEMORY_SCOPE_AGENT);
                    bad |= chkp(vh2[12][0]) | chkp(vh2[12][1])
                         | chkp(vl2[12][0]) | chkp(vl2[12][1]);
                }
#pragma unroll
                for (int kt = 0; kt < 12; kt++) {
                    bad |= chkp(vh2[kt][0]) | chkp(vh2[kt][1])
                         | chkp(vl2[kt][0]) | chkp(vl2[kt][1]);
                }
                if (__ballot(bad != 0) == 0ull) break;
                __builtin_amdgcn_s_sleep(2);
            }
            if (bad) {
#pragma unroll
                for (int kt = 0; kt < 13; kt++) {
                    vh2[kt][0] = sanq(vh2[kt][0]); vh2[kt][1] = sanq(vh2[kt][1]);
                    vl2[kt][0] = sanq(vl2[kt][0]); vl2[kt][1] = sanq(vl2[kt][1]);
                }
            }
            asm volatile("" ::: "memory");

            f32x4 aHH = gpre;
            f32x4 aHL = {0.f, 0.f, 0.f, 0.f};
            f32x4 aLH = {0.f, 0.f, 0.f, 0.f};
#pragma unroll
            for (int kt = 0; kt < 13; kt++) {
                f16x8 bhv = __builtin_bit_cast(f16x8, vh2[kt]);
                f16x8 blv = __builtin_bit_cast(f16x8, vl2[kt]);
                f16x8 wh = *(const f16x8*)&ahi[(kt * 64 + l) * 8];
                f16x8 wl = *(const f16x8*)&alo[(kt * 64 + l) * 8];
                aHH = __builtin_amdgcn_mfma_f32_16x16x32_f16(wh, bhv, aHH, 0, 0, 0);
                aHL = __builtin_amdgcn_mfma_f32_16x16x32_f16(wh, blv, aHL, 0, 0, 0);
                aLH = __builtin_amdgcn_mfma_f32_16x16x32_f16(wl, bhv, aLH, 0, 0, 0);
            }
            acc = aHH + (aHL + aLH) * (1.f / 2048.f);
        } else {
            acc = gpre;   // h(-1) = 0
        }

#pragma unroll
        for (int q = 0; q < 4; q++) gl[(4 * hi4 + q) * 17 + b] = acc[q];
        __syncthreads();

        const int jj = hi4;
        float gi = gl[( 0 + jj) * 17 + b];
        float gf = gl[( 4 + jj) * 17 + b];
        float gg = gl[( 8 + jj) * 17 + b];
        float go = gl[(12 + jj) * 17 + b];
        __syncthreads();

        float si = 1.f / (1.f + expf(-gi));
        float sf = 1.f / (1.f + expf(-gf));
        float tg = tanhf(gg);
        float so = 1.f / (1.f + expf(-go));
        float c  = sf * c_reg + si * tg;
        c_reg = c;
        float h  = so * tanhf(c);

        if (s < SS - 1) {
            _Float16 hh = (_Float16)h;
            _Float16 hl = (_Float16)((h - (float)hh) * 2048.f);
            unsigned uh = __builtin_bit_cast(unsigned short, hh);
            unsigned ul = __builtin_bit_cast(unsigned short, hl);
            unsigned ph = uh | (((unsigned)__shfl_down((int)uh, 16)) << 16);
            unsigned pl = ul | (((unsigned)__shfl_down((int)ul, 16)) << 16);
            if ((jj & 1) == 0) {
                int k0 = j0 + jj;
                int kt = k0 >> 5, ko = k0 & 31;
                int lg = ko >> 3, e = ko & 7;
                size_t u16idx = ((size_t)(s * 13 + kt) * 64 + (lg * 16 + b)) * 8 + e;
                __hip_atomic_store((unsigned*)(exh_d + u16idx), ph,
                                   __ATOMIC_RELAXED, __HIP_MEMORY_SCOPE_AGENT);
                __hip_atomic_store((unsigned*)(exl_d + u16idx), pl,
                                   __ATOMIC_RELAXED, __HIP_MEMORY_SCOPE_AGENT);
            }
        }

        hbuf[(size_t)(b * SS + time) * H2 + dir * HH + j0 + jj] = h;
    }
}

// ---------------- attention scores + fused row softmax/table/preds/nll ----------------
// ITILE=7 -> 15 i-tiles x 16 batches = 240 blocks (<= 256 CUs, all concurrent;
// the old 144-block grid left 44% of the machine idle). Row (b,i)'s 100 scores
// live in one block -> softmax fused. Ragged last tile (i0=98 -> 1 row) guarded.
#define ITILE 7
#define NTILE 15
__global__ __launch_bounds__(256) void attn_scores_softmax_kernel(
    const float* __restrict__ ua, const float* __restrict__ wa,
    const float* __restrict__ va, const float* __restrict__ out2,
    const int* __restrict__ head, float* __restrict__ outb,
    float* __restrict__ nll)
{
    int b  = blockIdx.x / NTILE;
    int i0 = (blockIdx.x % NTILE) * ITILE;
    int tid = threadIdx.x;
    __shared__ float ua_t[100][101];
    __shared__ float wa_t[ITILE][102];
    __shared__ float sacc[ITILE][101];
    __shared__ float va_t[100];
    __shared__ float h0[100];

    for (int p = tid; p < ITILE * 101; p += 256) ((float*)sacc)[p] = 0.f;
    if (tid < 100) h0[tid] = out2[(size_t)(b * SS + tid) * H2];

    for (int ht = 0; ht < 8; ht++) {
        int hh0 = ht * 100;
        __syncthreads();
        for (int p = tid; p < 100 * 100; p += 256) {
            int j = p / 100, hh = p % 100;
            ua_t[j][hh] = ua[(size_t)(b * SS + j) * H2 + hh0 + hh];
        }
        for (int p = tid; p < ITILE * 100; p += 256) {
            int il = p / 100, hh = p % 100;
            wa_t[il][hh] = (i0 + il + 1 < SS)
                ? wa[(size_t)(b * SS + i0 + il + 1) * H2 + hh0 + hh] : 0.f;
        }
        if (tid < 100) va_t[tid] = va[hh0 + tid];
        __syncthreads();
        for (int p = tid; p < ITILE * 100; p += 256) {
            int il = p / 100, j = p % 100;
            float acc = 0.f;
#pragma unroll 4
            for (int hh = 0; hh < 100; hh++) {
                float x = ua_t[j][hh] + wa_t[il][hh];
                float z = __expf(2.f * x);
                float th = 1.f - 2.f * __builtin_amdgcn_rcpf(z + 1.f);
                acc = fmaf(th, va_t[hh], acc);
            }
            sacc[il][j] += acc;
        }
    }
    __syncthreads();

    int wv = tid >> 6, ln = tid & 63;
    for (int il = wv; il < ITILE; il += 4) {
        int i = i0 + il;
        if (i > 98) continue;            // ragged last tile
        int bi = b * 99 + i;
        float h_t = h0[i + 1];
        int j1 = ln, j2 = ln + 64;
        float s1 = sacc[il][j1];
        if (h0[j1] == h_t) s1 = -10000.0f;
        float s2 = -1e30f;
        if (j2 < 100) {
            s2 = sacc[il][j2];
            if (h0[j2] == h_t) s2 = -10000.0f;
        }
        float v = s1; int vi = j1;
        if (s2 > v) { v = s2; vi = j2; }          // j1 < j2: ties keep j1
        for (int k = 32; k >= 1; k >>= 1) {
            float vo = __shfl_xor(v, k);
            int   io = __shfl_xor(vi, k);
            if (vo > v || (vo == v && io < vi)) { v = vo; vi = io; }
        }
        float m = v; int amax = vi;
        float e1 = __expf(s1 - m);
        float e2 = (j2 < 100) ? __expf(s2 - m) : 0.f;
        float sum = e1 + e2;
        for (int k = 32; k >= 1; k >>= 1) sum += __shfl_xor(sum, k);
        float inv = 1.f / sum;
        outb[1 + 1584 + (size_t)bi * 100 + j1] = e1 * inv;
        if (j2 < 100) outb[1 + 1584 + (size_t)bi * 100 + j2] = e2 * inv;
        if (ln == 0) {
            outb[1 + bi] = (float)amax;
            int gold = head[b * SS + i + 1];
            bool valid = (gold != -1);
            int gc = gold < 0 ? 0 : (gold > 99 ? 99 : gold);
            float sgc = sacc[il][gc];
            if (h0[gc] == h_t) sgc = -10000.0f;
            nll[bi] = valid ? -(sgc - m - logf(sum)) : 0.f;
        }
    }
}

// ---------------- final loss reduction ----------------
__global__ __launch_bounds__(128) void loss_kernel(
    const float* __restrict__ nll, const int* __restrict__ head,
    float* __restrict__ outb)
{
    __shared__ float red[128];
    int tid = threadIdx.x;
    float contrib = 0.f;
    if (tid < 99) {
        int i = tid;
        float tot = 0.f; int cv = 0;
        for (int b = 0; b < BB; b++) {
            tot += nll[b * 99 + i];
            cv += (head[b * SS + i + 1] != -1) ? 1 : 0;
        }
        int denom = cv > 0 ? cv : 1;
        contrib = tot / (float)denom;
    }
    red[tid] = contrib;
    __syncthreads();
    for (int off = 64; off >= 1; off >>= 1) {
        if (tid < off) red[tid] += red[tid + off];
        __syncthreads();
    }
    if (tid == 0) outb[0] = red[0];
}

// ---------------- launch (7 nodes) ----------------
extern "C" void kernel_launch(void* const* d_in, const int* in_sizes, int n_in,
                              void* d_out, int out_size, void* d_ws, size_t ws_size,
                              hipStream_t stream) {
    const int*   tok     = (const int*)d_in[0];
    const int*   pos     = (const int*)d_in[1];
    const int*   head    = (const int*)d_in[2];
    const float* word_W  = (const float*)d_in[3];
    const float* pos_W   = (const float*)d_in[4];
    const float* l0f_Wih = (const float*)d_in[5];
    const float* l0f_Whh = (const float*)d_in[6];
    const float* l0f_b   = (const float*)d_in[7];
    const float* l0b_Wih = (const float*)d_in[8];
    const float* l0b_Whh = (const float*)d_in[9];
    const float* l0b_b   = (const float*)d_in[10];
    const float* l1f_Wih = (const float*)d_in[11];
    const float* l1f_Whh = (const float*)d_in[12];
    const float* l1f_b   = (const float*)d_in[13];
    const float* l1b_Wih = (const float*)d_in[14];
    const float* l1b_Whh = (const float*)d_in[15];
    const float* l1b_b   = (const float*)d_in[16];
    const float* ua_W    = (const float*)d_in[17];
    const float* ua_b    = (const float*)d_in[18];
    const float* wa_W    = (const float*)d_in[19];
    const float* wa_b    = (const float*)d_in[20];
    const float* va_W    = (const float*)d_in[21];

    float* ws   = (float*)d_ws;
    float* gf   = ws + OFF_GF;   // g0f / g1f / ua
    float* gb   = ws + OFF_GB;   // g0b / g1b / wa
    float* h1   = ws + OFF_H1;
    float* out2 = ws + OFF_OUT2;
    float* nllb = ws + OFF_NLL;
    unsigned short* exhi = (unsigned short*)(ws + OFF_EXH);
    unsigned short* exlo = exhi + EX_U16_PER_PLANE;
    float* outf = (float*)d_out;

    // layer-0 projections: fused embedding + LDS-staged A + poison init
    gemm_l0_embed_dual<<<dim3(50, 25), 256, 0, stream>>>(
        tok, pos, word_W, pos_W,
        l0f_Wih, l0f_b, gf, l0b_Wih, l0b_b, gb,
        (unsigned int*)exhi, (int)EX_U16_PER_PLANE);
    // layer-0 recurrence
    lstm_layer_kernel<<<dim3(200), 64, 0, stream>>>(
        gf, gb, l0f_Whh, l0b_Whh, h1, exhi, exlo);
    // layer-1 projections (K=800) + exchange re-poison
    gemm_nt_mfma_dual<<<dim3(50, 25), 256, 0, stream>>>(
        h1, l1f_Wih, l1f_b, gf, l1b_Wih, l1b_b, gb, H2, G4,
        (unsigned int*)exhi, (int)EX_U16_PER_PLANE);
    // layer-1 recurrence
    lstm_layer_kernel<<<dim3(200), 64, 0, stream>>>(
        gf, gb, l1f_Whh, l1b_Whh, out2, exhi, exlo);
    // attention projections (K=800, R=800)
    gemm_nt_mfma_dual<<<dim3(26, 25), 256, 0, stream>>>(
        out2, ua_W, ua_b, gf, wa_W, wa_b, gb, H2, H2, nullptr, 0);
    // scores + fused softmax/table/preds/nll (240 blocks)
    attn_scores_softmax_kernel<<<dim3(BB * NTILE), 256, 0, stream>>>(
        gf, gb, va_W, out2, head, outf, nllb);
    // final loss
    loss_kernel<<<dim3(1), 128, 0, stream>>>(nllb, head, outf);
}